// Round 16
// baseline (158.282 us; speedup 1.0000x reference)
//
#include <hip/hip_runtime.h>

typedef float f32x2 __attribute__((ext_vector_type(2)));
typedef float f32x4 __attribute__((ext_vector_type(4)));
typedef float f32x16 __attribute__((ext_vector_type(16)));
typedef short bf16x8 __attribute__((ext_vector_type(8)));
typedef unsigned u32x2 __attribute__((ext_vector_type(2)));
typedef unsigned short u16;

#define S_LEN 4096
#define DMODEL 1024
#define NH 16
#define DK 64

// 1/sqrt(64) * log2(e): softmax runs in base-2 domain
#define SCALE_Q 0.18033688f

static __device__ __forceinline__ u16 f2bf(float x) {
  union { float f; unsigned u; } v; v.f = x;
  unsigned r = v.u + 0x7fffu + ((v.u >> 16) & 1u);  // RNE
  return (u16)(r >> 16);
}

static __device__ __forceinline__ float bf2f(u16 x) {
  union { unsigned u; float f; } v; v.u = ((unsigned)x) << 16;
  return v.f;
}

static __device__ __forceinline__ float asf(unsigned u) {
  union { unsigned u; float f; } v; v.u = u;
  return v.f;
}

#if __has_builtin(__builtin_amdgcn_exp2f)
#define EXP2F __builtin_amdgcn_exp2f
#else
#define EXP2F exp2f
#endif

static __device__ __forceinline__ unsigned pkbf(float lo, float hi) {
  unsigned r;
  asm("v_cvt_pk_bf16_f32 %0, %1, %2" : "=v"(r) : "v"(lo), "v"(hi));
  return r;
}

static __device__ __forceinline__ void plswap(unsigned& a, unsigned& b, int hi) {
#if __has_builtin(__builtin_amdgcn_permlane32_swap)
  u32x2 r = __builtin_amdgcn_permlane32_swap(a, b, false, false);
  a = r.x; b = r.y;
  (void)hi;
#else
  unsigned ax = __shfl_xor(a, 32), bx = __shfl_xor(b, 32);
  unsigned na = hi ? bx : a;
  unsigned nb = hi ? b : ax;
  a = na; b = nb;
#endif
}

static __device__ __forceinline__ void gload16(const void* g, void* l) {
  void* gg = (void*)g;
  __builtin_amdgcn_global_load_lds(
      (__attribute__((address_space(1))) void*)gg,
      (__attribute__((address_space(3))) void*)l, 16, 0, 0);
}

// ---------------------------------------------------------------------------
// prep: one launch. blocks [0,4096): 4x W (K,N) f32 -> Wt (N,K) bf16 (32x32
// transpose tiles). blocks [4096,7168): 3x f32 -> bf16 elementwise.
// ---------------------------------------------------------------------------
__global__ __launch_bounds__(256) void prep(const float* __restrict__ W0,
                                            const float* __restrict__ W1,
                                            const float* __restrict__ W2,
                                            const float* __restrict__ W3,
                                            u16* __restrict__ Wt,
                                            const float* __restrict__ Q,
                                            const float* __restrict__ K,
                                            const float* __restrict__ V,
                                            u16* __restrict__ Qbf) {
  __shared__ float t[32][33];
  const int b = blockIdx.x;
  const int tid = threadIdx.x;
  if (b < 4096) {
    const int z = b >> 10;
    const int rem = b & 1023;
    const float* W = (z == 0) ? W0 : (z == 1) ? W1 : (z == 2) ? W2 : W3;
    u16* dst = Wt + (size_t)z * DMODEL * DMODEL;
    const int x = tid & 31, y = tid >> 5;          // 32 x 8
    const int n0 = (rem & 31) * 32, k0 = (rem >> 5) * 32;
#pragma unroll
    for (int i = 0; i < 4; ++i)
      t[y + 8 * i][x] = W[(size_t)(k0 + y + 8 * i) * DMODEL + n0 + x];
    __syncthreads();
#pragma unroll
    for (int i = 0; i < 4; ++i)
      dst[(size_t)(n0 + y + 8 * i) * DMODEL + k0 + x] = f2bf(t[x][y + 8 * i]);
  } else {
    const int b2 = b - 4096;
    const int z = b2 >> 10;
    const int blk = b2 & 1023;
    const float* src = (z == 0) ? Q : (z == 1) ? K : V;
    u16* dst = Qbf + (size_t)z * S_LEN * DMODEL;
    const int n8 = S_LEN * DMODEL / 8;
    for (int i = blk * 256 + tid; i < n8; i += 1024 * 256) {
      float4 a = ((const float4*)src)[2 * i];
      float4 c = ((const float4*)src)[2 * i + 1];
      union { ushort4 u[2]; int4 q; } tt;
      tt.u[0].x = f2bf(a.x); tt.u[0].y = f2bf(a.y);
      tt.u[0].z = f2bf(a.z); tt.u[0].w = f2bf(a.w);
      tt.u[1].x = f2bf(c.x); tt.u[1].y = f2bf(c.y);
      tt.u[1].z = f2bf(c.z); tt.u[1].w = f2bf(c.w);
      ((int4*)dst)[i] = tt.q;
    }
  }
}

// ---------------------------------------------------------------------------
// pgemm: QKV projections, 128x128 tile, BK=64 elems (128B), 32x32x16 MFMAs,
// double-buffered counted-vmcnt. (R15-proven.)
// ---------------------------------------------------------------------------
__global__ __launch_bounds__(256) void pgemm(const u16* __restrict__ Abase,
                                             const u16* __restrict__ Btbase,
                                             const float* __restrict__ bq,
                                             const float* __restrict__ bk,
                                             const float* __restrict__ bv,
                                             void* __restrict__ outbase) {
  __shared__ __align__(16) char smem[65536];  // buf: A 16KB @0, B 16KB @16384
  const int nblk = gridDim.x, cpx = nblk >> 3;
  const int b0 = blockIdx.x;
  const int bid = (b0 & 7) * cpx + (b0 >> 3);   // XCD swizzle (nblk%8==0)
  const int z = bid >> 8;
  const int rem = bid & 255;
  const int nb = rem & 7, mb = rem >> 3;
  const int m0 = mb * 128, n0 = nb * 128;
  const int tid = threadIdx.x, lane = tid & 63, wid = tid >> 6;
  const int l31 = lane & 31, hi = lane >> 5;
  const int wm = (wid >> 1) * 64, wn = (wid & 1) * 64;
  const char* Ab = (const char*)(Abase + (size_t)z * S_LEN * DMODEL);
  const char* Bb = (const char*)(Btbase + (size_t)z * DMODEL * DMODEL);
  const float* bias = (z == 0) ? bq : (z == 1 ? bk : bv);
  const float scale = (z == 0) ? SCALE_Q : 1.0f;

  f32x16 acc[2][2] = {};

  // preload bias into registers; drain vmem so counted vmcnt is exact
  float bb2[2];
#pragma unroll
  for (int g = 0; g < 2; ++g) bb2[g] = bias[n0 + wn + g * 32 + l31];
  asm volatile("s_waitcnt vmcnt(0)" ::: "memory");

  const int r8 = tid >> 3;                               // 0..31
  const int colg = ((tid * 16) & 127) ^ ((r8 & 7) << 4);
  const char* gA = Ab + (size_t)(m0 + r8) * 2048 + colg;
  const char* gB = Bb + (size_t)(n0 + r8) * 2048 + colg;
  const int ldst = wid * 1024;

  auto stageAB = [&](int base) {
#pragma unroll
    for (int p = 0; p < 4; ++p)
      gload16(gA + p * 65536, smem + base + p * 4096 + ldst);
#pragma unroll
    for (int p = 0; p < 4; ++p)
      gload16(gB + p * 65536, smem + base + 16384 + p * 4096 + ldst);
    gA += 128; gB += 128;                      // BK = 64 elems = 128 BYTES
  };

  auto compute = [&](int base) {
    const char* Al = smem + base;
    const char* Bl = smem + base + 16384;
#pragma unroll
    for (int ks = 0; ks < 4; ++ks) {
      bf16x8 a2[2], b2[2];
#pragma unroll
      for (int f = 0; f < 2; ++f) {
        int row = wm + f * 32 + l31;
        a2[f] = *(const bf16x8*)(Al + row * 128 +
                                 ((ks * 32 + hi * 16) ^ ((row & 7) << 4)));
      }
#pragma unroll
      for (int g = 0; g < 2; ++g) {
        int row = wn + g * 32 + l31;
        b2[g] = *(const bf16x8*)(Bl + row * 128 +
                                 ((ks * 32 + hi * 16) ^ ((row & 7) << 4)));
      }
#pragma unroll
      for (int f = 0; f < 2; ++f)
#pragma unroll
        for (int g = 0; g < 2; ++g)
          acc[f][g] =
              __builtin_amdgcn_mfma_f32_32x32x16_bf16(a2[f], b2[g], acc[f][g], 0, 0, 0);
    }
  };

  auto body = [&](const int CUR, const int NXT, bool doStage) {
    __builtin_amdgcn_sched_barrier(0);          // pin stage below prior barrier
    if (doStage) {
      stageAB(NXT);
      asm volatile("s_waitcnt vmcnt(8)" ::: "memory");  // CUR's 8 complete
    } else {
      asm volatile("s_waitcnt vmcnt(0)" ::: "memory");
    }
    __builtin_amdgcn_s_barrier();
    compute(CUR);
    __builtin_amdgcn_s_barrier();
  };

  stageAB(0);                      // prologue: kt=0 -> buf0
  for (int kt = 0; kt < 16; kt += 2) {
    body(0, 32768, kt + 1 < 16);
    body(32768, 0, kt + 2 < 16);
  }

  // epilogue: 32x32 C/D layout: col = l31, row = (i&3) + 8*(i>>2) + 4*hi
#pragma unroll
  for (int f = 0; f < 2; ++f) {
#pragma unroll
    for (int g = 0; g < 2; ++g) {
      const int col = n0 + wn + g * 32 + l31;
      const int row0 = m0 + wm + f * 32 + 4 * hi;
      const float bb = bb2[g];
      if (z == 2) {
        // V: (H,64,S) transposed; 4 consecutive rows (s) -> one 8B store
        u16* ov = (u16*)outbase + (size_t)2 * S_LEN * DMODEL;
        u16* base = ov + ((size_t)(col >> 6) * DK + (col & 63)) * S_LEN;
#pragma unroll
        for (int q2 = 0; q2 < 4; ++q2) {
          const int row = row0 + 8 * q2;
          ushort4 u;
          u.x = f2bf(acc[f][g][4 * q2 + 0] + bb);
          u.y = f2bf(acc[f][g][4 * q2 + 1] + bb);
          u.z = f2bf(acc[f][g][4 * q2 + 2] + bb);
          u.w = f2bf(acc[f][g][4 * q2 + 3] + bb);
          *(ushort4*)(base + row) = u;
        }
      } else {
        u16* oq = (u16*)outbase + (size_t)z * S_LEN * DMODEL;
#pragma unroll
        for (int i = 0; i < 16; ++i) {
          const int row = row0 + (i & 3) + 8 * (i >> 2);
          oq[((size_t)(col >> 6) * S_LEN + row) * DK + (col & 63)] =
              f2bf((acc[f][g][i] + bb) * scale);
        }
      }
    }
  }
}

// ---------------------------------------------------------------------------
// ogemm2: out(4096,1024) f32 = normalize(Opart0+Opart1) @ WtO^T + bO, with
// the combine FUSED into A-staging: A-tile for K-step kt is exactly head kt
// (DK=64=BK), so each body reads both Opart halves (bf16), adds, multiplies
// by 1/(l0+l1), packs bf16, and ds_writes with write-side XOR swizzle.
// B (WtO) stays gload_lds double-buffered. vmcnt discipline: A-reg loads are
// issued BEFORE B's gloads; the compiler's A-use wait drains B(CUR) (older);
// explicit vmcnt(4)+lgkmcnt(0) before the barrier leaves only B(NXT) in
// flight and commits the ds_writes. 64x128 tile, grid 512 = 2 blocks/CU.
// ---------------------------------------------------------------------------
__global__ __launch_bounds__(256) void ogemm2(const u16* __restrict__ Op,
                                              const float* __restrict__ Lp,
                                              const u16* __restrict__ Bt,
                                              const float* __restrict__ bias,
                                              float* __restrict__ out) {
  __shared__ __align__(16) char smem[49152];  // buf: A 8KB @0, B 16KB @8192
  const int b0 = blockIdx.x;
  const int bid = (b0 & 7) * 64 + (b0 >> 3);    // XCD swizzle, 512%8==0
  const int nb = bid & 7, mb = bid >> 3;
  const int m0 = mb * 64, n0 = nb * 128;
  const int tid = threadIdx.x, lane = tid & 63, wid = tid >> 6;
  const int l31 = lane & 31, hi = lane >> 5;
  const int wm = (wid >> 1) * 32, wn = (wid & 1) * 64;
  const size_t halfO = (size_t)NH * S_LEN * DK;

  f32x16 acc[2] = {};

  float bb2[2];
#pragma unroll
  for (int g = 0; g < 2; ++g) bb2[g] = bias[n0 + wn + g * 32 + l31];
  asm volatile("s_waitcnt vmcnt(0)" ::: "memory");

  const int r8 = tid >> 3;   // 0..31: A row within 32-row half
  const int c8 = tid & 7;    // 16B chunk within 128B row
  const int colgB = ((tid * 16) & 127) ^ ((r8 & 7) << 4);
  const char* gB = (const char*)Bt + (size_t)(n0 + r8) * 2048 + colgB;
  const int ldstB = wid * 1024;

  auto stageB = [&](int base) {
#pragma unroll
    for (int p = 0; p < 4; ++p)
      gload16(gB + p * 65536, smem + base + 8192 + p * 4096 + ldstB);
    gB += 128;                                 // BK = 64 elems = 128 BYTES
  };

  // A loads for head kt: rows r8 and 32+r8 of this block's 64-row tile
  auto loadA = [&](int kt, int4& a0, int4& b0, int4& a1, int4& b1,
                   float& inv0, float& inv1) {
    const size_t base0 = ((size_t)kt * S_LEN + m0 + r8) * DK + c8 * 8;
    const size_t base1 = base0 + (size_t)32 * DK;
    a0 = *(const int4*)(Op + base0);
    b0 = *(const int4*)(Op + halfO + base0);
    a1 = *(const int4*)(Op + base1);
    b1 = *(const int4*)(Op + halfO + base1);
    const size_t lb0 = (size_t)kt * S_LEN + m0 + r8;
    inv0 = 1.f / (Lp[lb0] + Lp[(size_t)NH * S_LEN + lb0]);
    inv1 = 1.f / (Lp[lb0 + 32] + Lp[(size_t)NH * S_LEN + lb0 + 32]);
  };

  auto writeA = [&](int base, int4 a, int4 b, float inv, int row) {
    unsigned w[4];
#pragma unroll
    for (int j = 0; j < 4; ++j) {
      unsigned ua = ((unsigned*)&a)[j], ub = ((unsigned*)&b)[j];
      float lo = asf(ua << 16) + asf(ub << 16);
      float hh = asf(ua & 0xffff0000u) + asf(ub & 0xffff0000u);
      w[j] = pkbf(lo * inv, hh * inv);
    }
    const int addr = base + row * 128 + ((c8 * 16) ^ ((row & 7) << 4));
    *(int4*)(smem + addr) = *(int4*)w;         // ds_write_b128, 16B aligned
  };

  auto stageA = [&](int base, int kt) {
    int4 a0, b0, a1, b1; float i0, i1;
    loadA(kt, a0, b0, a1, b1, i0, i1);
    // NOTE: loads above are consumed below -> compiler drains them (and all
    // OLDER vmem, i.e. B(CUR)) before the converts.
    writeA(base, a0, b0, i0, r8);
    writeA(base, a1, b1, i1, 32 + r8);
  };

  auto compute = [&](int base) {
    const char* Al = smem + base;
    const char* Bl = smem + base + 8192;
#pragma unroll
    for (int ks = 0; ks < 4; ++ks) {
      int rowA = wm + l31;
      bf16x8 a2 = *(const bf16x8*)(Al + rowA * 128 +
                                   ((ks * 32 + hi * 16) ^ ((rowA & 7) << 4)));
      bf16x8 b2[2];
#pragma unroll
      for (int g = 0; g < 2; ++g) {
        int row = wn + g * 32 + l31;
        b2[g] = *(const bf16x8*)(Bl + row * 128 +
                                 ((ks * 32 + hi * 16) ^ ((row & 7) << 4)));
      }
#pragma unroll
      for (int g = 0; g < 2; ++g)
        acc[g] = __builtin_amdgcn_mfma_f32_32x32x16_bf16(a2, b2[g], acc[g], 0, 0, 0);
    }
  };

  auto body = [&](const int CUR, const int NXT, int ktn, bool doStage) {
    __builtin_amdgcn_sched_barrier(0);
    if (doStage) {
      int4 a0, b0, a1, b1; float i0, i1;
      loadA(ktn, a0, b0, a1, b1, i0, i1);      // A(t+1): 4 b128 + 2 scalar
      stageB(NXT);                             // B(t+1): 4 gload_lds
      writeA(NXT, a0, b0, i0, r8);             // waits A -> drains B(CUR) too
      writeA(NXT, a1, b1, i1, 32 + r8);
      asm volatile("s_waitcnt vmcnt(4) lgkmcnt(0)" ::: "memory");
    } else {
      asm volatile("s_waitcnt vmcnt(0) lgkmcnt(0)" ::: "memory");
    }
    __builtin_amdgcn_s_barrier();
    compute(CUR);
    __builtin_amdgcn_s_barrier();
  };

  // prologue: A(0)+B(0) -> buf0
  stageB(0);
  stageA(0, 0);
  asm volatile("s_waitcnt lgkmcnt(0)" ::: "memory");

  for (int kt = 0; kt < 16; kt += 2) {
    body(0, 24576, kt + 1, kt + 1 < 16);
    body(24576, 0, kt + 2, kt + 2 < 16);
  }

#pragma unroll
  for (int g = 0; g < 2; ++g) {
    const int col = n0 + wn + g * 32 + l31;
    const int row0 = m0 + wm + 4 * hi;
    const float bb = bb2[g];
#pragma unroll
    for (int i = 0; i < 16; ++i) {
      const int row = row0 + (i & 3) + 8 * (i >> 2);
      out[(size_t)row * DMODEL + col] = acc[g][i] + bb;
    }
  }
}

// ---------------------------------------------------------------------------
// Flash attention (R12-exact, proven 80.2us): swapped-QK^T, fixed-max base-2
// softmax, KV-split x2. 512-thread blocks (8 waves x 32 q-rows), grid 512.
// Counted-vmcnt double-barrier per 64-key tile, 32KB LDS -> 2 blocks/CU.
// ---------------------------------------------------------------------------
__global__ __launch_bounds__(512) void attn2(const u16* __restrict__ q,
                                             const u16* __restrict__ k,
                                             const u16* __restrict__ vt,
                                             u16* __restrict__ Opart,
                                             float* __restrict__ Lpart) {
  __shared__ __align__(16) char smem[32768];  // 2 bufs x (K 8KB + V^T 8KB)
  const int bid0 = blockIdx.x;
  const int bid = (bid0 & 7) * 64 + (bid0 >> 3);  // XCD swizzle, 512%8==0
  const int h = bid >> 5;
  const int kvh = (bid >> 4) & 1;
  const int qblk = bid & 15;
  const int tid = threadIdx.x;
  const int wid = tid >> 6, lane = tid & 63;
  const int l31 = lane & 31, hi = lane >> 5;

  const char* kpb = (const char*)k + (size_t)h * S_LEN * (DK * 2);
  const char* vtb = (const char*)vt + (size_t)h * DK * (S_LEN * 2);

  // Q B-fragments: col=q=lane&31, kdim d = 16*dt + 8*hi + j
  const int q0w = qblk * 256 + wid * 32;
  const u16* qrow = q + ((size_t)h * S_LEN + q0w + l31) * DK;
  bf16x8 qf[4];
#pragma unroll
  for (int dt = 0; dt < 4; ++dt)
    qf[dt] = *(const bf16x8*)(qrow + dt * 16 + hi * 8);

  f32x16 o0 = {}, o1 = {};   // O^T[d,q]: o0 = d 0..31, o1 = d 32..63
  f32x2 lacc2 = {0.f, 0.f};

  const int woff = wid << 10;     // each wave stages a contiguous 1KB chunk
  const int kt0 = kvh * 32;       // 32 tiles per half
  const int kt1 = kt0 + 32;

  // loop-invariant per-lane ds-read byte offsets (swizzled)
  const int swz = (l31 & 7) << 4;
  int dsa[4];
#pragma unroll
  for (int dt = 0; dt < 4; ++dt)
    dsa[dt] = (l31 << 7) + ((dt * 32 + hi * 16) ^ swz);

  // induction global staging pointers (1 K-load + 1 V-load per thread)
  const int lin = tid * 16;                       // 0..8176, covers 8KB
  const int sw = lin ^ (((lin >> 7) & 7) << 4);
  const char* gk = kpb + (size_t)kt0 * 8192 + sw;
  const char* gv = vtb + (size_t)(lin >> 7) * 8192 + (size_t)kt0 * 128 + (sw & 127);

  // prologue: stage tile kt0 into buf0
  gload16(gk, smem + woff);          gk += 8192;
  gload16(gv, smem + 8192 + woff);   gv += 128;

  auto body = [&](const int CUR, const int NXT, bool doStage) {
    if (doStage) {
      gload16(gk, smem + NXT + woff);          gk += 8192;
      gload16(gv, smem + NXT + 8192 + woff);   gv += 128;
      asm volatile("s_waitcnt vmcnt(2)" ::: "memory");  // CUR staged; NXT in flight
    } else {
      asm volatile("s_waitcnt vmcnt(0)" ::: "memory");
    }
    __builtin_amdgcn_s_barrier();   // all waves: CUR data ready

    const char* kb = smem + CUR;
    const char* vb = smem + CUR + 8192;

    // QK^T swapped: st[k,q], A=K (row=key), B=Q (col=q)
    f32x16 st0 = {}, st1 = {};
    __builtin_amdgcn_s_setprio(1);
#pragma unroll
    for (int dt = 0; dt < 4; ++dt) {
      bf16x8 k0 = *(const bf16x8*)(kb + dsa[dt]);
      bf16x8 k1 = *(const bf16x8*)(kb + 4096 + dsa[dt]);
      st0 = __builtin_amdgcn_mfma_f32_32x32x16_bf16(k0, qf[dt], st0, 0, 0, 0);
      st1 = __builtin_amdgcn_mfma_f32_32x32x16_bf16(k1, qf[dt], st1, 0, 0, 0);
    }
    __builtin_amdgcn_s_setprio(0);

    // fixed-max base-2 softmax fused with bf16 pack: w[i]=pk(exp2,exp2)
    unsigned w0[8], w1[8];
    f32x2 s2 = {0.f, 0.f};
#pragma unroll
    for (int i = 0; i < 8; ++i) {
      float a0 = EXP2F(st0[2 * i]), a1 = EXP2F(st0[2 * i + 1]);
      f32x2 t = {a0, a1}; s2 += t;
      w0[i] = pkbf(a0, a1);
    }
#pragma unroll
    for (int i = 0; i < 8; ++i) {
      float a0 = EXP2F(st1[2 * i]), a1 = EXP2F(st1[2 * i + 1]);
      f32x2 t = {a0, a1}; s2 += t;
      w1[i] = pkbf(a0, a1);
    }
    lacc2 += s2;

    // P^T fragments: permlane32_swap pairs (w[i], w[i+2])
    union UF { unsigned w[4]; bf16x8 v; };
    UF f[4];
#pragma unroll
    for (int g = 0; g < 2; ++g) {
#pragma unroll
      for (int j = 0; j < 2; ++j) {
        unsigned a = w0[4 * g + j], b = w0[4 * g + j + 2];
        plswap(a, b, hi);
        f[g].w[j] = a; f[g].w[j + 2] = b;
        unsigned c = w1[4 * g + j], d = w1[4 * g + j + 2];
        plswap(c, d, hi);
        f[2 + g].w[j] = c; f[2 + g].w[j + 2] = d;
      }
    }

    // PV: O^T[d,q] += V^T[d,k] P^T[k,q]
    __builtin_amdgcn_s_setprio(1);
#pragma unroll
    for (int kt2 = 0; kt2 < 4; ++kt2) {
      bf16x8 v0 = *(const bf16x8*)(vb + dsa[kt2]);
      bf16x8 v1 = *(const bf16x8*)(vb + 4096 + dsa[kt2]);
      o0 = __builtin_amdgcn_mfma_f32_32x32x16_bf16(v0, f[kt2].v, o0, 0, 0, 0);
      o1 = __builtin_amdgcn_mfma_f32_32x32x16_bf16(v1, f[kt2].v, o1, 0, 0, 0);
    }
    __builtin_amdgcn_s_setprio(0);

    __builtin_amdgcn_s_barrier();   // all waves done reading CUR
  };

  for (int kt = kt0; kt < kt1; kt += 2) {
    body(0, 16384, kt + 1 < kt1);
    body(16384, 0, kt + 2 < kt1);
  }

  // epilogue: store unnormalized partial O^T (bf16) + partial l (f32)
  const float lacc = lacc2.x + lacc2.y;
  const float lrow = lacc + __shfl_xor(lacc, 32);
  u16* Ob = Opart + ((((size_t)kvh * NH + h) * S_LEN) + q0w + l31) * DK;
#pragma unroll
  for (int g = 0; g < 4; ++g) {
    ushort4 u0, u1;
    u0.x = f2bf(o0[g * 4 + 0]); u0.y = f2bf(o0[g * 4 + 1]);
    u0.z = f2bf(o0[g * 4 + 2]); u0.w = f2bf(o0[g * 4 + 3]);
    *(ushort4*)(Ob + 8 * g + 4 * hi) = u0;
    u1.x = f2bf(o1[g * 4 + 0]); u1.y = f2bf(o1[g * 4 + 1]);
    u1.z = f2bf(o1[g * 4 + 2]); u1.w = f2bf(o1[g * 4 + 3]);
    *(ushort4*)(Ob + 32 + 8 * g + 4 * hi) = u1;
  }
  Lpart[((size_t)kvh * NH + h) * S_LEN + q0w + l31] = lrow;
}

// ---------------------------------------------------------------------------
extern "C" void kernel_launch(void* const* d_in, const int* in_sizes, int n_in,
                              void* d_out, int out_size, void* d_ws, size_t ws_size,
                              hipStream_t stream) {
  (void)in_sizes; (void)n_in; (void)out_size; (void)ws_size;
  const float* Q   = (const float*)d_in[0];
  const float* K   = (const float*)d_in[1];
  const float* V   = (const float*)d_in[2];
  const float* W_Q = (const float*)d_in[3];
  const float* b_Q = (const float*)d_in[4];
  const float* W_K = (const float*)d_in[5];
  const float* b_K = (const float*)d_in[6];
  const float* W_V = (const float*)d_in[7];
  const float* b_V = (const float*)d_in[8];
  const float* W_O = (const float*)d_in[9];
  const float* b_O = (const float*)d_in[10];
  float* out = (float*)d_out;

  char* ws = (char*)d_ws;
  const size_t MB = 1024 * 1024;
  u16* WtQ = (u16*)ws;                        // 4 x 2MB = [0, 8MB)
  u16* Qbf = (u16*)(ws + 8 * MB);             // 3 x 8MB = [8, 32MB); dead after pgemm
  u16* Opart = (u16*)(ws + 8 * MB);           // 2 x 8MB = [8, 24MB) bf16 (overlays Qbf)
  u16* qp   = (u16*)(ws + 40 * MB);           // (H,S,64)  [40,48)
  u16* kp   = qp + (size_t)S_LEN * DMODEL;    //           [48,56)
  u16* vtp  = kp + (size_t)S_LEN * DMODEL;    // (H,64,S)  [56,64)
  float* Lpart = (float*)(ws + 72 * MB);      // 2 x (H,S) f32 = 512KB

  prep<<<7168, 256, 0, stream>>>(W_Q, W_K, W_V, W_O, WtQ, Q, K, V, Qbf);

  pgemm<<<768, 256, 0, stream>>>(Qbf, WtQ, b_Q, b_K, b_V, qp);

  attn2<<<512, 512, 0, stream>>>(qp, kp, vtp, Opart, Lpart);

  ogemm2<<<512, 256, 0, stream>>>(Opart, Lpart,
                                  WtQ + (size_t)3 * DMODEL * DMODEL, b_O, out);
}

// Round 17
// 155.277 us; speedup vs baseline: 1.0194x; 1.0194x over previous
//
#include <hip/hip_runtime.h>

typedef float f32x2 __attribute__((ext_vector_type(2)));
typedef float f32x4 __attribute__((ext_vector_type(4)));
typedef float f32x16 __attribute__((ext_vector_type(16)));
typedef short bf16x8 __attribute__((ext_vector_type(8)));
typedef unsigned u32x2 __attribute__((ext_vector_type(2)));
typedef unsigned short u16;

#define S_LEN 4096
#define DMODEL 1024
#define NH 16
#define DK 64

// 1/sqrt(64) * log2(e): softmax runs in base-2 domain
#define SCALE_Q 0.18033688f

static __device__ __forceinline__ u16 f2bf(float x) {
  union { float f; unsigned u; } v; v.f = x;
  unsigned r = v.u + 0x7fffu + ((v.u >> 16) & 1u);  // RNE
  return (u16)(r >> 16);
}

static __device__ __forceinline__ float bf2f(u16 x) {
  union { unsigned u; float f; } v; v.u = ((unsigned)x) << 16;
  return v.f;
}

#if __has_builtin(__builtin_amdgcn_exp2f)
#define EXP2F __builtin_amdgcn_exp2f
#else
#define EXP2F exp2f
#endif

static __device__ __forceinline__ unsigned pkbf(float lo, float hi) {
  unsigned r;
  asm("v_cvt_pk_bf16_f32 %0, %1, %2" : "=v"(r) : "v"(lo), "v"(hi));
  return r;
}

static __device__ __forceinline__ void plswap(unsigned& a, unsigned& b, int hi) {
#if __has_builtin(__builtin_amdgcn_permlane32_swap)
  u32x2 r = __builtin_amdgcn_permlane32_swap(a, b, false, false);
  a = r.x; b = r.y;
  (void)hi;
#else
  unsigned ax = __shfl_xor(a, 32), bx = __shfl_xor(b, 32);
  unsigned na = hi ? bx : a;
  unsigned nb = hi ? b : ax;
  a = na; b = nb;
#endif
}

static __device__ __forceinline__ void gload16(const void* g, void* l) {
  void* gg = (void*)g;
  __builtin_amdgcn_global_load_lds(
      (__attribute__((address_space(1))) void*)gg,
      (__attribute__((address_space(3))) void*)l, 16, 0, 0);
}

// ---------------------------------------------------------------------------
// prep: one launch. blocks [0,4096): 4x W (K,N) f32 -> Wt (N,K) bf16 (32x32
// transpose tiles). blocks [4096,7168): 3x f32 -> bf16 elementwise.
// ---------------------------------------------------------------------------
__global__ __launch_bounds__(256) void prep(const float* __restrict__ W0,
                                            const float* __restrict__ W1,
                                            const float* __restrict__ W2,
                                            const float* __restrict__ W3,
                                            u16* __restrict__ Wt,
                                            const float* __restrict__ Q,
                                            const float* __restrict__ K,
                                            const float* __restrict__ V,
                                            u16* __restrict__ Qbf) {
  __shared__ float t[32][33];
  const int b = blockIdx.x;
  const int tid = threadIdx.x;
  if (b < 4096) {
    const int z = b >> 10;
    const int rem = b & 1023;
    const float* W = (z == 0) ? W0 : (z == 1) ? W1 : (z == 2) ? W2 : W3;
    u16* dst = Wt + (size_t)z * DMODEL * DMODEL;
    const int x = tid & 31, y = tid >> 5;          // 32 x 8
    const int n0 = (rem & 31) * 32, k0 = (rem >> 5) * 32;
#pragma unroll
    for (int i = 0; i < 4; ++i)
      t[y + 8 * i][x] = W[(size_t)(k0 + y + 8 * i) * DMODEL + n0 + x];
    __syncthreads();
#pragma unroll
    for (int i = 0; i < 4; ++i)
      dst[(size_t)(n0 + y + 8 * i) * DMODEL + k0 + x] = f2bf(t[x][y + 8 * i]);
  } else {
    const int b2 = b - 4096;
    const int z = b2 >> 10;
    const int blk = b2 & 1023;
    const float* src = (z == 0) ? Q : (z == 1) ? K : V;
    u16* dst = Qbf + (size_t)z * S_LEN * DMODEL;
    const int n8 = S_LEN * DMODEL / 8;
    for (int i = blk * 256 + tid; i < n8; i += 1024 * 256) {
      float4 a = ((const float4*)src)[2 * i];
      float4 c = ((const float4*)src)[2 * i + 1];
      union { ushort4 u[2]; int4 q; } tt;
      tt.u[0].x = f2bf(a.x); tt.u[0].y = f2bf(a.y);
      tt.u[0].z = f2bf(a.z); tt.u[0].w = f2bf(a.w);
      tt.u[1].x = f2bf(c.x); tt.u[1].y = f2bf(c.y);
      tt.u[1].z = f2bf(c.z); tt.u[1].w = f2bf(c.w);
      ((int4*)dst)[i] = tt.q;
    }
  }
}

// ---------------------------------------------------------------------------
// pgemm: QKV projections, 128x128 tile, BK=64 elems (128B), 32x32x16 MFMAs,
// double-buffered counted-vmcnt (attn2 skeleton). Bias PRELOADED + explicit
// vmcnt(0) drain before prologue stage so the hw vmcnt counter tracks ONLY
// staging loads. K-step stride = 128 BYTES.
// grid 768: z = bid>>8 selects Q/K/V; z=0/1 -> head-split bf16 (H,S,64)
// [z=0 scaled]; z=2 -> transposed bf16 (H,64,S). LDS 64KB -> 2 blocks/CU.
// ---------------------------------------------------------------------------
__global__ __launch_bounds__(256) void pgemm(const u16* __restrict__ Abase,
                                             const u16* __restrict__ Btbase,
                                             const float* __restrict__ bq,
                                             const float* __restrict__ bk,
                                             const float* __restrict__ bv,
                                             void* __restrict__ outbase) {
  __shared__ __align__(16) char smem[65536];  // buf: A 16KB @0, B 16KB @16384
  const int nblk = gridDim.x, cpx = nblk >> 3;
  const int b0 = blockIdx.x;
  const int bid = (b0 & 7) * cpx + (b0 >> 3);   // XCD swizzle (nblk%8==0)
  const int z = bid >> 8;
  const int rem = bid & 255;
  const int nb = rem & 7, mb = rem >> 3;
  const int m0 = mb * 128, n0 = nb * 128;
  const int tid = threadIdx.x, lane = tid & 63, wid = tid >> 6;
  const int l31 = lane & 31, hi = lane >> 5;
  const int wm = (wid >> 1) * 64, wn = (wid & 1) * 64;
  const char* Ab = (const char*)(Abase + (size_t)z * S_LEN * DMODEL);
  const char* Bb = (const char*)(Btbase + (size_t)z * DMODEL * DMODEL);
  const float* bias = (z == 0) ? bq : (z == 1 ? bk : bv);
  const float scale = (z == 0) ? SCALE_Q : 1.0f;

  f32x16 acc[2][2] = {};

  // preload bias into registers; drain vmem so counted vmcnt is exact
  float bb2[2];
#pragma unroll
  for (int g = 0; g < 2; ++g) bb2[g] = bias[n0 + wn + g * 32 + l31];
  asm volatile("s_waitcnt vmcnt(0)" ::: "memory");

  const int r8 = tid >> 3;                               // 0..31
  const int colg = ((tid * 16) & 127) ^ ((r8 & 7) << 4);
  const char* gA = Ab + (size_t)(m0 + r8) * 2048 + colg;
  const char* gB = Bb + (size_t)(n0 + r8) * 2048 + colg;
  const int ldst = wid * 1024;

  auto stageAB = [&](int base) {
#pragma unroll
    for (int p = 0; p < 4; ++p)
      gload16(gA + p * 65536, smem + base + p * 4096 + ldst);
#pragma unroll
    for (int p = 0; p < 4; ++p)
      gload16(gB + p * 65536, smem + base + 16384 + p * 4096 + ldst);
    gA += 128; gB += 128;                      // BK = 64 elems = 128 BYTES
  };

  auto compute = [&](int base) {
    const char* Al = smem + base;
    const char* Bl = smem + base + 16384;
#pragma unroll
    for (int ks = 0; ks < 4; ++ks) {
      bf16x8 a2[2], b2[2];
#pragma unroll
      for (int f = 0; f < 2; ++f) {
        int row = wm + f * 32 + l31;
        a2[f] = *(const bf16x8*)(Al + row * 128 +
                                 ((ks * 32 + hi * 16) ^ ((row & 7) << 4)));
      }
#pragma unroll
      for (int g = 0; g < 2; ++g) {
        int row = wn + g * 32 + l31;
        b2[g] = *(const bf16x8*)(Bl + row * 128 +
                                 ((ks * 32 + hi * 16) ^ ((row & 7) << 4)));
      }
#pragma unroll
      for (int f = 0; f < 2; ++f)
#pragma unroll
        for (int g = 0; g < 2; ++g)
          acc[f][g] =
              __builtin_amdgcn_mfma_f32_32x32x16_bf16(a2[f], b2[g], acc[f][g], 0, 0, 0);
    }
  };

  auto body = [&](const int CUR, const int NXT, bool doStage) {
    __builtin_amdgcn_sched_barrier(0);          // pin stage below prior barrier
    if (doStage) {
      stageAB(NXT);
      asm volatile("s_waitcnt vmcnt(8)" ::: "memory");  // CUR's 8 complete
    } else {
      asm volatile("s_waitcnt vmcnt(0)" ::: "memory");
    }
    __builtin_amdgcn_s_barrier();
    compute(CUR);
    __builtin_amdgcn_s_barrier();
  };

  stageAB(0);                      // prologue: kt=0 -> buf0
  for (int kt = 0; kt < 16; kt += 2) {
    body(0, 32768, kt + 1 < 16);
    body(32768, 0, kt + 2 < 16);
  }

  // epilogue: 32x32 C/D layout: col = l31, row = (i&3) + 8*(i>>2) + 4*hi
#pragma unroll
  for (int f = 0; f < 2; ++f) {
#pragma unroll
    for (int g = 0; g < 2; ++g) {
      const int col = n0 + wn + g * 32 + l31;
      const int row0 = m0 + wm + f * 32 + 4 * hi;
      const float bb = bb2[g];
      if (z == 2) {
        // V: (H,64,S) transposed; 4 consecutive rows (s) -> one 8B store
        u16* ov = (u16*)outbase + (size_t)2 * S_LEN * DMODEL;
        u16* base = ov + ((size_t)(col >> 6) * DK + (col & 63)) * S_LEN;
#pragma unroll
        for (int q2 = 0; q2 < 4; ++q2) {
          const int row = row0 + 8 * q2;
          ushort4 u;
          u.x = f2bf(acc[f][g][4 * q2 + 0] + bb);
          u.y = f2bf(acc[f][g][4 * q2 + 1] + bb);
          u.z = f2bf(acc[f][g][4 * q2 + 2] + bb);
          u.w = f2bf(acc[f][g][4 * q2 + 3] + bb);
          *(ushort4*)(base + row) = u;
        }
      } else {
        u16* oq = (u16*)outbase + (size_t)z * S_LEN * DMODEL;
#pragma unroll
        for (int i = 0; i < 16; ++i) {
          const int row = row0 + (i & 3) + 8 * (i >> 2);
          oq[((size_t)(col >> 6) * S_LEN + row) * DK + (col & 63)] =
              f2bf((acc[f][g][i] + bb) * scale);
        }
      }
    }
  }
}

// ---------------------------------------------------------------------------
// ogemm: out(4096,1024) f32 = comb(4096,1024)bf16 @ WtO^T + bO.
// 64x128 tile, grid 512 = 2 blocks/CU, double-buffered (48KB) counted-vmcnt.
// ---------------------------------------------------------------------------
__global__ __launch_bounds__(256) void ogemm(const u16* __restrict__ A,
                                             const u16* __restrict__ Bt,
                                             const float* __restrict__ bias,
                                             float* __restrict__ out) {
  __shared__ __align__(16) char smem[49152];  // buf: A 8KB @0, B 16KB @8192
  const int b0 = blockIdx.x;
  const int bid = (b0 & 7) * 64 + (b0 >> 3);    // XCD swizzle, 512%8==0
  const int nb = bid & 7, mb = bid >> 3;
  const int m0 = mb * 64, n0 = nb * 128;
  const int tid = threadIdx.x, lane = tid & 63, wid = tid >> 6;
  const int l31 = lane & 31, hi = lane >> 5;
  const int wm = (wid >> 1) * 32, wn = (wid & 1) * 64;

  f32x16 acc[2] = {};

  float bb2[2];
#pragma unroll
  for (int g = 0; g < 2; ++g) bb2[g] = bias[n0 + wn + g * 32 + l31];
  asm volatile("s_waitcnt vmcnt(0)" ::: "memory");

  const int r8 = tid >> 3;
  const int colg = ((tid * 16) & 127) ^ ((r8 & 7) << 4);
  const char* gA = (const char*)A + (size_t)(m0 + r8) * 2048 + colg;
  const char* gB = (const char*)Bt + (size_t)(n0 + r8) * 2048 + colg;
  const int ldst = wid * 1024;

  auto stageAB = [&](int base) {
#pragma unroll
    for (int p = 0; p < 2; ++p)
      gload16(gA + p * 65536, smem + base + p * 4096 + ldst);
#pragma unroll
    for (int p = 0; p < 4; ++p)
      gload16(gB + p * 65536, smem + base + 8192 + p * 4096 + ldst);
    gA += 128; gB += 128;                      // BK = 64 elems = 128 BYTES
  };

  auto compute = [&](int base) {
    const char* Al = smem + base;
    const char* Bl = smem + base + 8192;
#pragma unroll
    for (int ks = 0; ks < 4; ++ks) {
      int rowA = wm + l31;
      bf16x8 a2 = *(const bf16x8*)(Al + rowA * 128 +
                                   ((ks * 32 + hi * 16) ^ ((rowA & 7) << 4)));
      bf16x8 b2[2];
#pragma unroll
      for (int g = 0; g < 2; ++g) {
        int row = wn + g * 32 + l31;
        b2[g] = *(const bf16x8*)(Bl + row * 128 +
                                 ((ks * 32 + hi * 16) ^ ((row & 7) << 4)));
      }
#pragma unroll
      for (int g = 0; g < 2; ++g)
        acc[g] = __builtin_amdgcn_mfma_f32_32x32x16_bf16(a2, b2[g], acc[g], 0, 0, 0);
    }
  };

  auto body = [&](const int CUR, const int NXT, bool doStage) {
    __builtin_amdgcn_sched_barrier(0);
    if (doStage) {
      stageAB(NXT);
      asm volatile("s_waitcnt vmcnt(6)" ::: "memory");
    } else {
      asm volatile("s_waitcnt vmcnt(0)" ::: "memory");
    }
    __builtin_amdgcn_s_barrier();
    compute(CUR);
    __builtin_amdgcn_s_barrier();
  };

  stageAB(0);
  for (int kt = 0; kt < 16; kt += 2) {
    body(0, 24576, kt + 1 < 16);
    body(24576, 0, kt + 2 < 16);
  }

#pragma unroll
  for (int g = 0; g < 2; ++g) {
    const int col = n0 + wn + g * 32 + l31;
    const int row0 = m0 + wm + 4 * hi;
    const float bb = bb2[g];
#pragma unroll
    for (int i = 0; i < 16; ++i) {
      const int row = row0 + (i & 3) + 8 * (i >> 2);
      out[(size_t)row * DMODEL + col] = acc[g][i] + bb;
    }
  }
}

// ---------------------------------------------------------------------------
// Flash attention (R12-exact, proven 80.2us): swapped-QK^T, fixed-max base-2
// softmax, KV-split x2. 512-thread blocks (8 waves x 32 q-rows), grid 512.
// Counted-vmcnt double-barrier per 64-key tile, 32KB LDS -> 2 blocks/CU.
// ---------------------------------------------------------------------------
__global__ __launch_bounds__(512) void attn2(const u16* __restrict__ q,
                                             const u16* __restrict__ k,
                                             const u16* __restrict__ vt,
                                             u16* __restrict__ Opart,
                                             float* __restrict__ Lpart) {
  __shared__ __align__(16) char smem[32768];  // 2 bufs x (K 8KB + V^T 8KB)
  const int bid0 = blockIdx.x;
  const int bid = (bid0 & 7) * 64 + (bid0 >> 3);  // XCD swizzle, 512%8==0
  const int h = bid >> 5;
  const int kvh = (bid >> 4) & 1;
  const int qblk = bid & 15;
  const int tid = threadIdx.x;
  const int wid = tid >> 6, lane = tid & 63;
  const int l31 = lane & 31, hi = lane >> 5;

  const char* kpb = (const char*)k + (size_t)h * S_LEN * (DK * 2);
  const char* vtb = (const char*)vt + (size_t)h * DK * (S_LEN * 2);

  // Q B-fragments: col=q=lane&31, kdim d = 16*dt + 8*hi + j
  const int q0w = qblk * 256 + wid * 32;
  const u16* qrow = q + ((size_t)h * S_LEN + q0w + l31) * DK;
  bf16x8 qf[4];
#pragma unroll
  for (int dt = 0; dt < 4; ++dt)
    qf[dt] = *(const bf16x8*)(qrow + dt * 16 + hi * 8);

  f32x16 o0 = {}, o1 = {};   // O^T[d,q]: o0 = d 0..31, o1 = d 32..63
  f32x2 lacc2 = {0.f, 0.f};

  const int woff = wid << 10;     // each wave stages a contiguous 1KB chunk
  const int kt0 = kvh * 32;       // 32 tiles per half
  const int kt1 = kt0 + 32;

  // loop-invariant per-lane ds-read byte offsets (swizzled)
  const int swz = (l31 & 7) << 4;
  int dsa[4];
#pragma unroll
  for (int dt = 0; dt < 4; ++dt)
    dsa[dt] = (l31 << 7) + ((dt * 32 + hi * 16) ^ swz);

  // induction global staging pointers (1 K-load + 1 V-load per thread)
  const int lin = tid * 16;                       // 0..8176, covers 8KB
  const int sw = lin ^ (((lin >> 7) & 7) << 4);
  const char* gk = kpb + (size_t)kt0 * 8192 + sw;
  const char* gv = vtb + (size_t)(lin >> 7) * 8192 + (size_t)kt0 * 128 + (sw & 127);

  // prologue: stage tile kt0 into buf0
  gload16(gk, smem + woff);          gk += 8192;
  gload16(gv, smem + 8192 + woff);   gv += 128;

  auto body = [&](const int CUR, const int NXT, bool doStage) {
    if (doStage) {
      gload16(gk, smem + NXT + woff);          gk += 8192;
      gload16(gv, smem + NXT + 8192 + woff);   gv += 128;
      asm volatile("s_waitcnt vmcnt(2)" ::: "memory");  // CUR staged; NXT in flight
    } else {
      asm volatile("s_waitcnt vmcnt(0)" ::: "memory");
    }
    __builtin_amdgcn_s_barrier();   // all waves: CUR data ready

    const char* kb = smem + CUR;
    const char* vb = smem + CUR + 8192;

    // QK^T swapped: st[k,q], A=K (row=key), B=Q (col=q)
    f32x16 st0 = {}, st1 = {};
    __builtin_amdgcn_s_setprio(1);
#pragma unroll
    for (int dt = 0; dt < 4; ++dt) {
      bf16x8 k0 = *(const bf16x8*)(kb + dsa[dt]);
      bf16x8 k1 = *(const bf16x8*)(kb + 4096 + dsa[dt]);
      st0 = __builtin_amdgcn_mfma_f32_32x32x16_bf16(k0, qf[dt], st0, 0, 0, 0);
      st1 = __builtin_amdgcn_mfma_f32_32x32x16_bf16(k1, qf[dt], st1, 0, 0, 0);
    }
    __builtin_amdgcn_s_setprio(0);

    // fixed-max base-2 softmax fused with bf16 pack: w[i]=pk(exp2,exp2)
    unsigned w0[8], w1[8];
    f32x2 s2 = {0.f, 0.f};
#pragma unroll
    for (int i = 0; i < 8; ++i) {
      float a0 = EXP2F(st0[2 * i]), a1 = EXP2F(st0[2 * i + 1]);
      f32x2 t = {a0, a1}; s2 += t;
      w0[i] = pkbf(a0, a1);
    }
#pragma unroll
    for (int i = 0; i < 8; ++i) {
      float a0 = EXP2F(st1[2 * i]), a1 = EXP2F(st1[2 * i + 1]);
      f32x2 t = {a0, a1}; s2 += t;
      w1[i] = pkbf(a0, a1);
    }
    lacc2 += s2;

    // P^T fragments: permlane32_swap pairs (w[i], w[i+2])
    union UF { unsigned w[4]; bf16x8 v; };
    UF f[4];
#pragma unroll
    for (int g = 0; g < 2; ++g) {
#pragma unroll
      for (int j = 0; j < 2; ++j) {
        unsigned a = w0[4 * g + j], b = w0[4 * g + j + 2];
        plswap(a, b, hi);
        f[g].w[j] = a; f[g].w[j + 2] = b;
        unsigned c = w1[4 * g + j], d = w1[4 * g + j + 2];
        plswap(c, d, hi);
        f[2 + g].w[j] = c; f[2 + g].w[j + 2] = d;
      }
    }

    // PV: O^T[d,q] += V^T[d,k] P^T[k,q]
    __builtin_amdgcn_s_setprio(1);
#pragma unroll
    for (int kt2 = 0; kt2 < 4; ++kt2) {
      bf16x8 v0 = *(const bf16x8*)(vb + dsa[kt2]);
      bf16x8 v1 = *(const bf16x8*)(vb + 4096 + dsa[kt2]);
      o0 = __builtin_amdgcn_mfma_f32_32x32x16_bf16(v0, f[kt2].v, o0, 0, 0, 0);
      o1 = __builtin_amdgcn_mfma_f32_32x32x16_bf16(v1, f[kt2].v, o1, 0, 0, 0);
    }
    __builtin_amdgcn_s_setprio(0);

    __builtin_amdgcn_s_barrier();   // all waves done reading CUR
  };

  for (int kt = kt0; kt < kt1; kt += 2) {
    body(0, 16384, kt + 1 < kt1);
    body(16384, 0, kt + 2 < kt1);
  }

  // epilogue: store unnormalized partial O^T (bf16) + partial l (f32)
  const float lacc = lacc2.x + lacc2.y;
  const float lrow = lacc + __shfl_xor(lacc, 32);
  u16* Ob = Opart + ((((size_t)kvh * NH + h) * S_LEN) + q0w + l31) * DK;
#pragma unroll
  for (int g = 0; g < 4; ++g) {
    ushort4 u0, u1;
    u0.x = f2bf(o0[g * 4 + 0]); u0.y = f2bf(o0[g * 4 + 1]);
    u0.z = f2bf(o0[g * 4 + 2]); u0.w = f2bf(o0[g * 4 + 3]);
    *(ushort4*)(Ob + 8 * g + 4 * hi) = u0;
    u1.x = f2bf(o1[g * 4 + 0]); u1.y = f2bf(o1[g * 4 + 1]);
    u1.z = f2bf(o1[g * 4 + 2]); u1.w = f2bf(o1[g * 4 + 3]);
    *(ushort4*)(Ob + 32 + 8 * g + 4 * hi) = u1;
  }
  Lpart[((size_t)kvh * NH + h) * S_LEN + q0w + l31] = lrow;
}

// ---------------------------------------------------------------------------
// combine: comb[q][h*64+d] = sum_kv(O_kv) / sum_kv(l_kv), bf16 partials (x2)
// ---------------------------------------------------------------------------
__global__ __launch_bounds__(256) void combine(const u16* __restrict__ Op,
                                               const float* __restrict__ Lp,
                                               u16* __restrict__ comb) {
  const int id = blockIdx.x * 256 + threadIdx.x;   // 1M threads
  const int h = id >> 16;
  const int rem = id & 65535;
  const int qv = rem >> 4;
  const int d4 = (rem & 15) << 2;
  const size_t str = (size_t)NH * S_LEN * DK;
  const size_t base = (((size_t)h * S_LEN) + qv) * DK + d4;
  float o0 = 0.f, o1 = 0.f, o2 = 0.f, o3 = 0.f, l = 0.f;
#pragma unroll
  for (int kv = 0; kv < 2; ++kv) {
    ushort4 u = *(const ushort4*)(Op + kv * str + base);
    o0 += bf2f(u.x); o1 += bf2f(u.y); o2 += bf2f(u.z); o3 += bf2f(u.w);
    l += Lp[(size_t)kv * NH * S_LEN + (size_t)h * S_LEN + qv];
  }
  const float inv = 1.f / l;
  ushort4 u;
  u.x = f2bf(o0 * inv);
  u.y = f2bf(o1 * inv);
  u.z = f2bf(o2 * inv);
  u.w = f2bf(o3 * inv);
  *(ushort4*)(comb + (size_t)qv * DMODEL + h * DK + d4) = u;
}

// ---------------------------------------------------------------------------
extern "C" void kernel_launch(void* const* d_in, const int* in_sizes, int n_in,
                              void* d_out, int out_size, void* d_ws, size_t ws_size,
                              hipStream_t stream) {
  (void)in_sizes; (void)n_in; (void)out_size; (void)ws_size;
  const float* Q   = (const float*)d_in[0];
  const float* K   = (const float*)d_in[1];
  const float* V   = (const float*)d_in[2];
  const float* W_Q = (const float*)d_in[3];
  const float* b_Q = (const float*)d_in[4];
  const float* W_K = (const float*)d_in[5];
  const float* b_K = (const float*)d_in[6];
  const float* W_V = (const float*)d_in[7];
  const float* b_V = (const float*)d_in[8];
  const float* W_O = (const float*)d_in[9];
  const float* b_O = (const float*)d_in[10];
  float* out = (float*)d_out;

  char* ws = (char*)d_ws;
  const size_t MB = 1024 * 1024;
  u16* WtQ = (u16*)ws;                        // 4 x 2MB = [0, 8MB)
  u16* Qbf = (u16*)(ws + 8 * MB);             // 3 x 8MB = [8, 32MB); dead after pgemm
  u16* Opart = (u16*)(ws + 8 * MB);           // 2 x 8MB = [8, 24MB) bf16 (overlays Qbf)
  u16* qp   = (u16*)(ws + 40 * MB);           // (H,S,64)  [40,48)
  u16* kp   = qp + (size_t)S_LEN * DMODEL;    //           [48,56)
  u16* vtp  = kp + (size_t)S_LEN * DMODEL;    // (H,64,S)  [56,64)
  u16* comb = vtp + (size_t)S_LEN * DMODEL;   // (S,1024)  [64,72)
  float* Lpart = (float*)(ws + 72 * MB);      // 2 x (H,S) f32 = 512KB

  prep<<<7168, 256, 0, stream>>>(W_Q, W_K, W_V, W_O, WtQ, Q, K, V, Qbf);

  pgemm<<<768, 256, 0, stream>>>(Qbf, WtQ, b_Q, b_K, b_V, qp);

  attn2<<<512, 512, 0, stream>>>(qp, kp, vtp, Opart, Lpart);
  combine<<<4096, 256, 0, stream>>>(Opart, Lpart, comb);

  ogemm<<<512, 256, 0, stream>>>(comb, WtQ + (size_t)3 * DMODEL * DMODEL,
                                 b_O, out);
}